// Round 6
// baseline (200.920 us; speedup 1.0000x reference)
//
#include <hip/hip_runtime.h>

#define HID 768
#define NTHREADS 256
#define WPB 4    // waves per block

// ---- kernel 1: resolve paths into a packed, d-major slot table -------------
// packed[d*T + t] = (node << 2) | (bit << 1) | valid.
// Tiny: T*D ~ 41k slots; reads 800 KB of path tables (L2/L3-resident).
// This removes the target -> mask -> node dependent-load chain from the
// gather kernel AND lets us order work d-major so that concurrently
// dispatched waves gather the SAME hot rows (root at d=0: 1 row for all
// 2048 tokens; d=1: 2 rows; ...) -> L1/L2 broadcast hits.
__global__ __launch_bounds__(NTHREADS) void huffman_pack_kernel(
    const int*  __restrict__ target,      // [T]
    const int*  __restrict__ path_nodes,  // [V, D]
    const int*  __restrict__ path_bits,   // [V, D]
    const void* __restrict__ path_mask,   // [V, D] bool (byte OR int32 layout)
    int*        __restrict__ packed,      // [D*T], d-major
    int T, int D)
{
    const int idx = blockIdx.x * NTHREADS + threadIdx.x;   // idx = d*T + t
    if (idx >= T * D) return;
    const int d = idx / T;
    const int t = idx - d * T;

    // Mask layout detect: mask[0,0..3] all true (min Huffman depth >> 4),
    // byte layout reads 0x01010101, int32 layout reads 1.
    const bool mask_is_byte = (*(const unsigned int*)path_mask) > 1u;

    const int  v  = target[t];                  // coalesced across t
    const long pr = (long)v * D + d;
    const bool valid = mask_is_byte
        ? (((const unsigned char*)path_mask)[pr] != 0)
        : (((const int*)path_mask)[pr] != 0);

    int p = 0;
    if (valid) {
        const int n = path_nodes[pr];
        const int b = path_bits[pr];
        p = (n << 2) | (b << 1) | 1;
    }
    packed[idx] = p;
}

// ---- kernel 2: one wave per valid (t,d) slot, d-major ----------------------
// Wave w of block bx owns slot = bx*4 + w  (d = slot/T, t = slot%T).
// Invalid slots exit before any gather (valid steps are ~66% of slots).
// Per valid slot: 1 packed load -> 6 coalesced float4 W-loads + 6 float2
// h-loads -> 24 FMAs -> 6-level butterfly -> delta-form double-softmax CE.
// Per-block LDS combine of 4 wave sums -> at most one atomicAdd per block.
__global__ __launch_bounds__(NTHREADS) void huffman_gather_kernel(
    const float* __restrict__ hidden,     // [T, H]
    const float* __restrict__ node_W,     // [V-1, H, 2]
    const float* __restrict__ node_b,     // [V-1, 2]
    const int*   __restrict__ packed,     // [D*T], d-major
    float*       __restrict__ out,        // [1], pre-zeroed
    int T, int nslots)
{
    const int wave = threadIdx.x >> 6;
    const int lane = threadIdx.x & 63;
    const int slot = blockIdx.x * WPB + wave;

    float lsum = 0.0f;

    if (slot < nslots) {
        const int p = packed[slot];           // same addr across wave -> 1 line
        if (p & 1) {
            const int d = slot / T;
            const int t = slot - d * T;
            const int n = p >> 2;

            const float4* __restrict__ w4 =
                (const float4*)(node_W + (long)n * (HID * 2));
            const float2* __restrict__ h2 =
                (const float2*)(hidden + (long)t * HID);

            float acc0 = 0.0f, acc1 = 0.0f;
            #pragma unroll
            for (int j = 0; j < HID / 2 / 64; ++j) {   // 6 iters
                const int q  = j * 64 + lane;          // k-pair: k = 2q, 2q+1
                const float4 w = w4[q];                // W[n,2q,{0,1}],W[n,2q+1,{0,1}]
                const float2 h = h2[q];
                acc0 += h.x * w.x + h.y * w.z;
                acc1 += h.x * w.y + h.y * w.w;
            }

            #pragma unroll
            for (int off = 32; off > 0; off >>= 1) {
                acc0 += __shfl_xor(acc0, off, 64);
                acc1 += __shfl_xor(acc1, off, 64);
            }

            // delta-form double-softmax CE (verified exact in R5):
            // p0 = sigmoid(l0-l1), p1 = 1-p0, ce = log(e^p0+e^p1) - p_bit.
            const float delta = (acc0 - acc1)
                              + (node_b[n * 2 + 0] - node_b[n * 2 + 1]);
            const float p0  = 1.0f / (1.0f + __expf(-delta));
            const float p1  = 1.0f - p0;
            const float lse = __logf(__expf(p0) + __expf(p1));
            const float pb  = (p & 2) ? p1 : p0;
            lsum = lse - pb;                  // full sum in all lanes
        }
    }

    __shared__ float wsum[WPB];
    if (lane == 0) wsum[wave] = lsum;
    __syncthreads();
    if (threadIdx.x == 0) {
        const float tot = (wsum[0] + wsum[1]) + (wsum[2] + wsum[3]);
        if (tot != 0.0f) atomicAdd(out, tot);
    }
}

extern "C" void kernel_launch(void* const* d_in, const int* in_sizes, int n_in,
                              void* d_out, int out_size, void* d_ws, size_t ws_size,
                              hipStream_t stream) {
    const float* hidden     = (const float*)d_in[0];
    const int*   target     = (const int*)d_in[1];
    const float* node_W     = (const float*)d_in[2];
    const float* node_b     = (const float*)d_in[3];
    const int*   path_nodes = (const int*)d_in[4];
    const int*   path_bits  = (const int*)d_in[5];
    const void*  path_mask  = (const void*)d_in[6];
    float* out = (float*)d_out;

    const int T   = in_sizes[0] / HID;        // B*S = 2048
    const int Vm1 = in_sizes[3] / 2;          // V-1 = 9999
    const int V   = Vm1 + 1;
    const int D   = in_sizes[4] / V;          // padded path depth (~20)

    int* packed = (int*)d_ws;                 // D*T ints (~164 KB)
    const int nslots = T * D;

    // out is re-poisoned (0xAA) before every timed call; zero it for atomics.
    hipMemsetAsync(d_out, 0, sizeof(float), stream);

    const int pblocks = (nslots + NTHREADS - 1) / NTHREADS;
    huffman_pack_kernel<<<dim3(pblocks), dim3(NTHREADS), 0, stream>>>(
        target, path_nodes, path_bits, path_mask, packed, T, D);

    const int gblocks = (nslots + WPB - 1) / WPB;
    huffman_gather_kernel<<<dim3(gblocks), dim3(NTHREADS), 0, stream>>>(
        hidden, node_W, node_b, packed, out, T, nslots);
}